// Round 1
// baseline (773.778 us; speedup 1.0000x reference)
//
#include <hip/hip_runtime.h>

// ---------------- CSR build ----------------

__global__ void hist_k(const int* __restrict__ dst, int* __restrict__ counts, int E){
  int e = blockIdx.x*blockDim.x + threadIdx.x;
  if(e<E) atomicAdd(&counts[dst[e]], 1);
}

__global__ __launch_bounds__(1024) void scan1_k(const int* __restrict__ counts, int* __restrict__ excl,
                                                int* __restrict__ partials, int N){
  __shared__ int tmp[1024];
  int tid = threadIdx.x;
  int i = blockIdx.x*1024 + tid;
  int v = (i<N)? counts[i] : 0;
  tmp[tid] = v;
  __syncthreads();
  for(int off=1; off<1024; off<<=1){
    int t = (tid>=off)? tmp[tid-off] : 0;
    __syncthreads();
    tmp[tid] += t;
    __syncthreads();
  }
  if(i<N) excl[i] = tmp[tid] - v;
  if(tid==1023) partials[blockIdx.x] = tmp[tid];
}

__global__ void scan2_k(int* __restrict__ partials, int NB){
  __shared__ int tmp[64];
  int tid = threadIdx.x;
  int v = (tid<NB)? partials[tid] : 0;
  tmp[tid] = v;
  __syncthreads();
  for(int off=1; off<64; off<<=1){
    int t = (tid>=off)? tmp[tid-off] : 0;
    __syncthreads();
    tmp[tid] += t;
    __syncthreads();
  }
  if(tid<NB) partials[tid] = tmp[tid] - v;
}

__global__ __launch_bounds__(1024) void scan3_k(int* __restrict__ row_ptr, const int* __restrict__ partials,
                                                int* __restrict__ cursors, int N, int E){
  int i = blockIdx.x*1024 + threadIdx.x;
  if(i<N){
    int r = row_ptr[i] + partials[blockIdx.x];
    row_ptr[i] = r;
    cursors[i] = r;
  }
  if(i==0) row_ptr[N] = E;
}

// packs (orig_edge_id, src_node) into one 8B record -> single load in agg_k
__global__ void scatter_k(const int* __restrict__ src, const int* __restrict__ dst, int* __restrict__ cursors,
                          int2* __restrict__ edat, int E){
  int e = blockIdx.x*blockDim.x + threadIdx.x;
  if(e<E){
    int d = dst[e];
    int p = atomicAdd(&cursors[d], 1);
    edat[p] = make_int2(e, src[e]);
  }
}

// one-time weight transpose: W[128][256] (out-major) -> Wt[256][128] (k-major)
__global__ void wt_k(const float* __restrict__ W, float* __restrict__ Wt){
  int idx = blockIdx.x*256 + threadIdx.x;   // 0..32767
  int k = idx >> 7, o = idx & 127;
  Wt[idx] = W[o*256 + k];
}

// ---------------- per-layer kernels ----------------

// a_src[n] = aw[0:128].h[n]; a_dst[n] = aw[128:256].h[n] + ab. One wave/node.
__global__ void attn_k(const float* __restrict__ h, const float* __restrict__ aw, const float* __restrict__ ab,
                       float* __restrict__ a_src, float* __restrict__ a_dst, int N){
  int gid = blockIdx.x*blockDim.x + threadIdx.x;
  int n = gid >> 6, lane = gid & 63;
  if(n >= N) return;
  float2 hv = ((const float2*)(h + (size_t)n*128))[lane];
  float2 wa = ((const float2*)aw)[lane];
  float2 wb = ((const float2*)(aw+128))[lane];
  float s = hv.x*wa.x + hv.y*wa.y;
  float t = hv.x*wb.x + hv.y*wb.y;
  #pragma unroll
  for(int off=32; off>0; off>>=1){
    s += __shfl_xor(s, off, 64);
    t += __shfl_xor(t, off, 64);
  }
  if(lane==0){ a_src[n] = s; a_dst[n] = t + ab[0]; }
}

// One wave per dst node. Logits for deg<=64 land in registers via one coalesced
// int2 load, in-register shfl softmax. Weighted gather runs DUAL-EDGE: the wave
// splits into two 32-lane halves, each half reads a full 512B efeats row as
// float4 (dwordx4). Halves the gather instruction count AND the bpermute count
// per edge vs the float2 whole-wave scheme.
__global__ __launch_bounds__(256) void agg_k(const float* __restrict__ efeats,
    const float* __restrict__ a_src, const float* __restrict__ a_dst,
    const int* __restrict__ row_ptr, const int2* __restrict__ edat,
    float* __restrict__ z, int N){
  int gid = blockIdx.x*blockDim.x + threadIdx.x;
  int n = gid >> 6, lane = gid & 63;
  if(n >= N) return;
  int half = lane >> 5, l32 = lane & 31;
  int beg = row_ptr[n], end = row_ptr[n+1];
  int deg = end - beg;
  if(deg <= 0){
    if(half==0) ((float4*)z)[(size_t)n*32 + l32] = make_float4(0.f,0.f,0.f,0.f);
    return;
  }
  float adn = a_dst[n];

  // ---- phase A: logits for first chunk in registers
  int i = beg + lane;
  bool valid = i < end;
  int2 es = valid ? edat[i] : make_int2(0,0);
  int perm_reg = es.x;
  float e_reg = valid ? fmaxf(a_src[es.y] + adn, 0.f) : -1e30f;

  float m = e_reg;
  #pragma unroll
  for(int off=32; off>0; off>>=1) m = fmaxf(m, __shfl_xor(m, off, 64));
  for(int c = beg + 64; c < end; c += 64){           // rare deg>64 path
    int ii = c + lane;
    float ev = (ii < end) ? fmaxf(a_src[edat[ii].y] + adn, 0.f) : -1e30f;
    #pragma unroll
    for(int off=32; off>0; off>>=1) ev = fmaxf(ev, __shfl_xor(ev, off, 64));
    m = fmaxf(m, ev);
  }

  float ex_reg = valid ? __expf(e_reg - m) : 0.f;
  float s = ex_reg;
  #pragma unroll
  for(int off=32; off>0; off>>=1) s += __shfl_xor(s, off, 64);
  for(int c = beg + 64; c < end; c += 64){           // rare deg>64 path
    int ii = c + lane;
    float ev = (ii < end) ? __expf(fmaxf(a_src[edat[ii].y] + adn, 0.f) - m) : 0.f;
    #pragma unroll
    for(int off=32; off>0; off>>=1) ev += __shfl_xor(ev, off, 64);
    s += ev;
  }
  float inv = 1.f / s;

  // ---- phase B: dual-edge float4 gather. half h of the wave owns edge j+h.
  const float4* ef4 = (const float4*)efeats;
  float4 acc = make_float4(0.f,0.f,0.f,0.f);
  int cnt = min(deg, 64);
  int j = 0;
  for(; j + 8 <= cnt; j += 8){                       // 8 edges / 4 loads in flight
    float p0 = __shfl(ex_reg, j+half,   64); int r0 = __shfl(perm_reg, j+half,   64);
    float p1 = __shfl(ex_reg, j+2+half, 64); int r1 = __shfl(perm_reg, j+2+half, 64);
    float p2 = __shfl(ex_reg, j+4+half, 64); int r2 = __shfl(perm_reg, j+4+half, 64);
    float p3 = __shfl(ex_reg, j+6+half, 64); int r3 = __shfl(perm_reg, j+6+half, 64);
    float4 f0 = ef4[(size_t)r0*32 + l32];
    float4 f1 = ef4[(size_t)r1*32 + l32];
    float4 f2 = ef4[(size_t)r2*32 + l32];
    float4 f3 = ef4[(size_t)r3*32 + l32];
    acc.x += p0*f0.x; acc.y += p0*f0.y; acc.z += p0*f0.z; acc.w += p0*f0.w;
    acc.x += p1*f1.x; acc.y += p1*f1.y; acc.z += p1*f1.z; acc.w += p1*f1.w;
    acc.x += p2*f2.x; acc.y += p2*f2.y; acc.z += p2*f2.z; acc.w += p2*f2.w;
    acc.x += p3*f3.x; acc.y += p3*f3.y; acc.z += p3*f3.z; acc.w += p3*f3.w;
  }
  for(; j + 2 <= cnt; j += 2){                       // pair tail
    float p = __shfl(ex_reg, j+half, 64); int r = __shfl(perm_reg, j+half, 64);
    float4 f = ef4[(size_t)r*32 + l32];
    acc.x += p*f.x; acc.y += p*f.y; acc.z += p*f.z; acc.w += p*f.w;
  }
  if(j < cnt){                                       // single last edge (half 0 only)
    float p = __shfl(ex_reg, j, 64); int r = __shfl(perm_reg, j, 64);
    if(half==0){
      float4 f = ef4[(size_t)r*32 + l32];
      acc.x += p*f.x; acc.y += p*f.y; acc.z += p*f.z; acc.w += p*f.w;
    }
  }
  for(int c = beg + 64; c < end; c += 64){           // rare deg>64 path
    int ii = c + lane;
    bool v2 = ii < end;
    int2 es2 = v2 ? edat[ii] : make_int2(0,0);
    int pr = es2.x;
    float er = v2 ? __expf(fmaxf(a_src[es2.y] + adn, 0.f) - m) : 0.f;
    int cc = min(end - c, 64);
    int jj = 0;
    for(; jj + 2 <= cc; jj += 2){
      float p = __shfl(er, jj+half, 64); int r = __shfl(pr, jj+half, 64);
      float4 f = ef4[(size_t)r*32 + l32];
      acc.x += p*f.x; acc.y += p*f.y; acc.z += p*f.z; acc.w += p*f.w;
    }
    if(jj < cc){
      float p = __shfl(er, jj, 64); int r = __shfl(pr, jj, 64);
      if(half==0){
        float4 f = ef4[(size_t)r*32 + l32];
        acc.x += p*f.x; acc.y += p*f.y; acc.z += p*f.z; acc.w += p*f.w;
      }
    }
  }

  // combine halves, normalize, store (lanes 0..31 write the full 512B row)
  acc.x += __shfl_xor(acc.x, 32, 64);
  acc.y += __shfl_xor(acc.y, 32, 64);
  acc.z += __shfl_xor(acc.z, 32, 64);
  acc.w += __shfl_xor(acc.w, 32, 64);
  if(half==0){
    acc.x *= inv; acc.y *= inv; acc.z *= inv; acc.w *= inv;
    ((float4*)z)[(size_t)n*32 + l32] = acc;
  }
}

// out[n][o] = relu(bias[o] + sum_k W[o][k]*x[n][k]), x = cat(h, z), K=256.
// 128 nodes x 128 outs per block, 256 threads, 8x8 micro-tile.
// k-major LDS (b128 reads only); the two 4-wide chunks per thread sit 64 apart
// so a wave's 16 chunks cover all 32 banks exactly twice -> conflict-free.
// Staging is register double-buffered: next K-slab's global loads are issued
// before the FMA phase so HBM latency hides under ~4096 cy of compute.
__global__ __launch_bounds__(256) void update_k(const float* __restrict__ h, const float* __restrict__ z,
                                                const float* __restrict__ Wt, const float* __restrict__ bias,
                                                float* __restrict__ out, int N){
  __shared__ float xsT[32][132];   // [k][node]
  __shared__ float ws[32][132];    // [k][out]
  int tid = threadIdx.x;
  int tx = tid & 15;               // out group: {tx*4..+3} U {64+tx*4..+3}
  int ty = tid >> 4;               // node group: {ty*4..+3} U {64+ty*4..+3}
  int n0 = blockIdx.x * 128;

  int sn  = tid >> 1;              // x-stage: node 0..127
  int skc = (tid & 1) * 16;        // x-stage: k offset
  int wkk = tid >> 3;              // w-stage: k row 0..31
  int woc = (tid & 7) * 4;         // w-stage: col base (step 32 per chunk)

  float4 xv4[4], wv4[4];
  {
    int node = n0 + sn;
    bool v = node < N;
    const float* sp = h + (size_t)node*128 + skc;
    #pragma unroll
    for(int jj=0;jj<4;jj++) xv4[jj] = v ? ((const float4*)sp)[jj] : make_float4(0.f,0.f,0.f,0.f);
    const float* wp = Wt + (size_t)wkk*128 + woc;
    #pragma unroll
    for(int jj=0;jj<4;jj++) wv4[jj] = *(const float4*)(wp + jj*32);
  }

  float acc[8][8];
  #pragma unroll
  for(int i=0;i<8;i++)
    #pragma unroll
    for(int j2=0;j2<8;j2++) acc[i][j2] = 0.f;

  for(int kb=0; kb<256; kb+=32){
    #pragma unroll
    for(int jj=0;jj<4;jj++){
      int kq = skc + jj*4;
      xsT[kq+0][sn] = xv4[jj].x;
      xsT[kq+1][sn] = xv4[jj].y;
      xsT[kq+2][sn] = xv4[jj].z;
      xsT[kq+3][sn] = xv4[jj].w;
      *(float4*)&ws[wkk][woc + jj*32] = wv4[jj];
    }
    __syncthreads();

    if(kb + 32 < 256){             // issue next slab's loads; waits land at next ds_write
      int kb2 = kb + 32;
      int node = n0 + sn;
      bool v = node < N;
      const float* sp = (kb2 < 128) ? h + (size_t)node*128 + kb2 + skc
                                    : z + (size_t)node*128 + (kb2-128) + skc;
      #pragma unroll
      for(int jj=0;jj<4;jj++) xv4[jj] = v ? ((const float4*)sp)[jj] : make_float4(0.f,0.f,0.f,0.f);
      const float* wp = Wt + (size_t)(kb2 + wkk)*128 + woc;
      #pragma unroll
      for(int jj=0;jj<4;jj++) wv4[jj] = *(const float4*)(wp + jj*32);
    }

    #pragma unroll 8
    for(int k=0;k<32;k++){
      float4 x0 = *(const float4*)&xsT[k][ty*4];
      float4 x1 = *(const float4*)&xsT[k][64 + ty*4];
      float4 w0 = *(const float4*)&ws[k][tx*4];
      float4 w1 = *(const float4*)&ws[k][64 + tx*4];
      float xv[8] = {x0.x,x0.y,x0.z,x0.w, x1.x,x1.y,x1.z,x1.w};
      float wv[8] = {w0.x,w0.y,w0.z,w0.w, w1.x,w1.y,w1.z,w1.w};
      #pragma unroll
      for(int i=0;i<8;i++)
        #pragma unroll
        for(int j2=0;j2<8;j2++)
          acc[i][j2] += xv[i]*wv[j2];
    }
    __syncthreads();
  }

  const float4* b4 = (const float4*)bias;
  float4 bb0 = b4[tx];             // outs tx*4..+3
  float4 bb1 = b4[16 + tx];        // outs 64+tx*4..+3
  #pragma unroll
  for(int i=0;i<8;i++){
    int n = n0 + ((i<4) ? (ty*4 + i) : (64 + ty*4 + (i-4)));
    if(n >= N) continue;
    float4 r0, r1;
    r0.x = fmaxf(acc[i][0]+bb0.x, 0.f);
    r0.y = fmaxf(acc[i][1]+bb0.y, 0.f);
    r0.z = fmaxf(acc[i][2]+bb0.z, 0.f);
    r0.w = fmaxf(acc[i][3]+bb0.w, 0.f);
    r1.x = fmaxf(acc[i][4]+bb1.x, 0.f);
    r1.y = fmaxf(acc[i][5]+bb1.y, 0.f);
    r1.z = fmaxf(acc[i][6]+bb1.z, 0.f);
    r1.w = fmaxf(acc[i][7]+bb1.w, 0.f);
    *(float4*)(out + (size_t)n*128 + tx*4)      = r0;
    *(float4*)(out + (size_t)n*128 + 64 + tx*4) = r1;
  }
}

// ---------------- driver ----------------

extern "C" void kernel_launch(void* const* d_in, const int* in_sizes, int n_in,
                              void* d_out, int out_size, void* d_ws, size_t ws_size,
                              hipStream_t stream){
  const float* nfeats = (const float*)d_in[0];
  const float* efeats = (const float*)d_in[1];
  const float* Ww0 = (const float*)d_in[2];
  const float* Wb0 = (const float*)d_in[3];
  const float* aw0 = (const float*)d_in[4];
  const float* ab0 = (const float*)d_in[5];
  const float* Ww1 = (const float*)d_in[6];
  const float* Wb1 = (const float*)d_in[7];
  const float* aw1 = (const float*)d_in[8];
  const float* ab1 = (const float*)d_in[9];
  const int* src = (const int*)d_in[10];
  const int* dst = (const int*)d_in[11];
  int E = in_sizes[10];
  int N = in_sizes[0] / 128;

  char* base = (char*)d_ws;
  size_t off = 0;
  auto take = [&](size_t bytes) -> char* {
    char* p = base + off;
    off = (off + bytes + 255) & ~(size_t)255;
    return p;
  };
  int*   counts  = (int*)take((size_t)N*4);
  int*   row_ptr = (int*)take((size_t)(N+1)*4);
  int*   cursors = (int*)take((size_t)N*4);
  int*   partials= (int*)take(256);
  int2*  edat    = (int2*)take((size_t)E*8);
  float* a_src   = (float*)take((size_t)N*4);
  float* a_dst   = (float*)take((size_t)N*4);
  float* zbuf    = (float*)take((size_t)N*128*4);
  float* h1      = (float*)take((size_t)N*128*4);
  float* Wt0     = (float*)take((size_t)256*128*4);
  float* Wt1     = (float*)take((size_t)256*128*4);

  int NB = (N + 1023)/1024;   // 49 for N=50000 (must be <= 64 for scan2_k)

  hipMemsetAsync(counts, 0, (size_t)N*4, stream);
  wt_k<<<128, 256, 0, stream>>>(Ww0, Wt0);
  wt_k<<<128, 256, 0, stream>>>(Ww1, Wt1);
  hist_k<<<(E+255)/256, 256, 0, stream>>>(dst, counts, E);
  scan1_k<<<NB, 1024, 0, stream>>>(counts, row_ptr, partials, N);
  scan2_k<<<1, 64, 0, stream>>>(partials, NB);
  scan3_k<<<NB, 1024, 0, stream>>>(row_ptr, partials, cursors, N, E);
  scatter_k<<<(E+255)/256, 256, 0, stream>>>(src, dst, cursors, edat, E);

  int agrid = (N + 3)/4;   // one wave per node, 4 waves per block
  int ugrid = (N + 127)/128;
  // layer 1
  attn_k<<<agrid, 256, 0, stream>>>(nfeats, aw0, ab0, a_src, a_dst, N);
  agg_k<<<agrid, 256, 0, stream>>>(efeats, a_src, a_dst, row_ptr, edat, zbuf, N);
  update_k<<<ugrid, 256, 0, stream>>>(nfeats, zbuf, Wt0, Wb0, h1, N);
  // layer 2
  attn_k<<<agrid, 256, 0, stream>>>(h1, aw1, ab1, a_src, a_dst, N);
  agg_k<<<agrid, 256, 0, stream>>>(efeats, a_src, a_dst, row_ptr, edat, zbuf, N);
  update_k<<<ugrid, 256, 0, stream>>>(h1, zbuf, Wt1, Wb1, (float*)d_out, N);
}